// Round 1
// 832.789 us; speedup vs baseline: 1.0139x; 1.0139x over previous
//
#include <hip/hip_runtime.h>
#include <math.h>

#define VOC 50000
#define EMB 300
#define BSZ 256
#define CTX 6
#define KNEG 10
#define ROW_VECS (VOC / 4)                       // 12500 float4 per one-hot row
#define NROWS (BSZ + BSZ * CTX + BSZ * KNEG)     // 4352
#define CHUNK_VECS 1024                          // 16 KB per (row,chunk) block
#define NCHUNKS ((ROW_VECS + CHUNK_VECS - 1) / CHUNK_VECS)   // 13

typedef float floatx4 __attribute__((ext_vector_type(4)));

// ---- init: out_idx[r] = -1 for all rows (padded vi rows stay -1) ----
__global__ __launch_bounds__(256) void init_kernel(int* __restrict__ out_idx) {
    int i = blockIdx.x * 256 + threadIdx.x;
    if (i < NROWS) out_idx[i] = -1;
}

// ---- chunk-parallel scan with generational early-exit ----
// blockIdx.x = row, blockIdx.y = chunk (x-major dispatch => all chunk-g blocks
// are dispatched before chunk-(g+1); later generations skip resolved rows via
// one agent-scope atomic load). No intra-block round loop, no barriers on the
// streaming path: every chunk's 16 KB of loads is fully independent -> HBM-BW
// bound instead of round-trip-latency bound. Stale flag reads across XCD L2s
// only cost extra reads, never correctness (exactly one lane grid-wide ever
// writes a given out_idx[r]).
__global__ __launch_bounds__(256) void scan_chunks_kernel(
        const floatx4* __restrict__ vo,
        const floatx4* __restrict__ vi,
        const floatx4* __restrict__ neg,
        int* __restrict__ out_idx) {
    const int r   = blockIdx.x;
    const int gen = blockIdx.y;

    __shared__ int s_skip;
    if (gen > 0) {
        if (threadIdx.x == 0)
            s_skip = (__hip_atomic_load(&out_idx[r], __ATOMIC_RELAXED,
                                        __HIP_MEMORY_SCOPE_AGENT) >= 0);
        __syncthreads();
        if (s_skip) return;
    }

    const floatx4* __restrict__ row;
    if (r < BSZ)                 row = vo  + (size_t)r * ROW_VECS;
    else if (r < BSZ + BSZ*CTX)  row = vi  + (size_t)(r - BSZ) * ROW_VECS;
    else                         row = neg + (size_t)(r - BSZ - BSZ*CTX) * ROW_VECS;

    const int base = gen * CHUNK_VECS;
    const int t = threadIdx.x;
    floatx4 v[4];
    int     j[4];
#pragma unroll
    for (int u = 0; u < 4; ++u) {
        j[u] = base + u * 256 + t;
        if (j[u] < ROW_VECS) v[u] = __builtin_nontemporal_load(&row[j[u]]);
        else                 v[u] = (floatx4)(0.f, 0.f, 0.f, 0.f);
    }
#pragma unroll
    for (int u = 0; u < 4; ++u) {
        if (v[u].x != 0.0f || v[u].y != 0.0f || v[u].z != 0.0f || v[u].w != 0.0f) {
            int col = j[u] * 4;
            if (v[u].x != 0.0f)      col += 0;
            else if (v[u].y != 0.0f) col += 1;
            else if (v[u].z != 0.0f) col += 2;
            else                     col += 3;
            __hip_atomic_store(&out_idx[r], col, __ATOMIC_RELAXED,
                               __HIP_MEMORY_SCOPE_AGENT);
        }
    }
}

__device__ __forceinline__ float log_sigmoid(float x) {
    return fminf(x, 0.0f) - log1pf(expf(-fabsf(x)));   // stable
}

// One wave per batch element. All gathers issued with max MLP: 6 context rows
// branchless (weight 0 for padding), 10 negative rows into independent
// accumulators. Writes a per-batch partial instead of a contended atomicAdd.
__global__ __launch_bounds__(64) void cbow_loss_kernel(
        const int* __restrict__ idx_vo,
        const int* __restrict__ idx_vi,
        const int* __restrict__ idx_neg,
        const float* __restrict__ V,
        const float* __restrict__ U,
        float* __restrict__ partial) {
    const int b = blockIdx.x;
    const int lane = threadIdx.x;   // blockDim.x == 64

    const int ivo = idx_vo[b];
    int ivi[CTX];
#pragma unroll
    for (int c = 0; c < CTX; ++c) ivi[c] = idx_vi[b * CTX + c];
    int ing[KNEG];
#pragma unroll
    for (int k = 0; k < KNEG; ++k) ing[k] = idx_neg[b * KNEG + k];

    int cnt = 0;
    float w[CTX];
    int   safe[CTX];
#pragma unroll
    for (int c = 0; c < CTX; ++c) {
        w[c] = (ivi[c] >= 0) ? 1.0f : 0.0f;
        safe[c] = (ivi[c] >= 0) ? ivi[c] : 0;
        cnt += (ivi[c] >= 0) ? 1 : 0;
    }
    const float inv_cnt = 1.0f / (float)cnt;   // cnt >= 1 (lengths >= 1)

    float vo_e[5] = {0.f, 0.f, 0.f, 0.f, 0.f};
    const float* __restrict__ vrow = V + (long)ivo * EMB;
#pragma unroll
    for (int j = 0; j < 5; ++j) {
        int d = lane + j * 64;
        if (d < EMB) vo_e[j] = vrow[d];
    }

    float vi_e[5] = {0.f, 0.f, 0.f, 0.f, 0.f};
#pragma unroll
    for (int c = 0; c < CTX; ++c) {
        const float* __restrict__ urow = U + (long)safe[c] * EMB;
#pragma unroll
        for (int j = 0; j < 5; ++j) {
            int d = lane + j * 64;
            if (d < EMB) vi_e[j] += w[c] * urow[d];
        }
    }

    float pd[KNEG];
#pragma unroll
    for (int k = 0; k < KNEG; ++k) pd[k] = 0.f;
#pragma unroll
    for (int k = 0; k < KNEG; ++k) {
        const float* __restrict__ urow = U + (long)ing[k] * EMB;
#pragma unroll
        for (int j = 0; j < 5; ++j) {
            int d = lane + j * 64;
            if (d < EMB) pd[k] += vo_e[j] * urow[d];
        }
    }

    float dot = 0.f;
#pragma unroll
    for (int j = 0; j < 5; ++j) dot += vo_e[j] * (vi_e[j] * inv_cnt);
#pragma unroll
    for (int off = 32; off > 0; off >>= 1) dot += __shfl_down(dot, off, 64);

#pragma unroll
    for (int k = 0; k < KNEG; ++k) {
#pragma unroll
        for (int off = 32; off > 0; off >>= 1) pd[k] += __shfl_down(pd[k], off, 64);
    }

    if (lane == 0) {
        float right = 0.f;
#pragma unroll
        for (int k = 0; k < KNEG; ++k) right += log_sigmoid(-pd[k]);
        float left = log_sigmoid(dot);
        partial[b] = -(left + right);
    }
}

// ---- final reduce: mean of 256 partials, single plain store ----
__global__ __launch_bounds__(256) void reduce_kernel(
        const float* __restrict__ partial, float* __restrict__ out) {
    const int t = threadIdx.x;           // 256 == BSZ
    float v = partial[t];
#pragma unroll
    for (int off = 32; off > 0; off >>= 1) v += __shfl_down(v, off, 64);
    __shared__ float s[4];
    if ((t & 63) == 0) s[t >> 6] = v;
    __syncthreads();
    if (t == 0) out[0] = (s[0] + s[1] + s[2] + s[3]) * (1.0f / (float)BSZ);
}

extern "C" void kernel_launch(void* const* d_in, const int* in_sizes, int n_in,
                              void* d_out, int out_size, void* d_ws, size_t ws_size,
                              hipStream_t stream) {
    const float* vo  = (const float*)d_in[0];   // [B, VOC]
    const float* vi  = (const float*)d_in[1];   // [B, CTX, VOC]
    const float* neg = (const float*)d_in[2];   // [B, K, VOC]
    const float* V   = (const float*)d_in[3];   // [VOC, EMB]
    const float* U   = (const float*)d_in[4];   // [VOC, EMB]
    float* out = (float*)d_out;

    int*   idx_all = (int*)d_ws;                // [NROWS]: vo | vi | neg
    int*   idx_vo  = idx_all;
    int*   idx_vi  = idx_all + BSZ;
    int*   idx_neg = idx_all + BSZ + BSZ * CTX;
    float* partial = (float*)((char*)d_ws + ((NROWS * sizeof(int) + 255) & ~(size_t)255));

    init_kernel<<<(NROWS + 255) / 256, 256, 0, stream>>>(idx_all);
    scan_chunks_kernel<<<dim3(NROWS, NCHUNKS), 256, 0, stream>>>(
        (const floatx4*)vo, (const floatx4*)vi, (const floatx4*)neg, idx_all);
    cbow_loss_kernel<<<BSZ, 64, 0, stream>>>(idx_vo, idx_vi, idx_neg, V, U, partial);
    reduce_kernel<<<1, 256, 0, stream>>>(partial, out);
}